// Round 2
// baseline (777.497 us; speedup 1.0000x reference)
//
#include <hip/hip_runtime.h>
#include <hip/hip_bf16.h>

#define HH 96
#define WW 96
#define NPX 9216          // HH*WW
#define NC 21             // classes
#define NCHUNK 32
#define NI 288            // NPX/NCHUNK
#define CP 24             // channels padded to 24 for b128 reads
#define RAD 35
#define TAPS 71

// ---------- dtype probe: kstd[0]=70.0 -> f32 word 0x428C0000, bf16 pair 0x428C428C ----------
__global__ void detect_kernel(const unsigned int* __restrict__ kstd_raw, int* __restrict__ flag){
    if (threadIdx.x == 0){
        unsigned int w = kstd_raw[0];
        *flag = ((w & 0xFFFFu) != 0u) ? 1 : 0;   // 1 = inputs are bf16
    }
}

// ---------- promote input array to f32 (branch on runtime flag, wave-uniform) ----------
__global__ __launch_bounds__(256) void convert_kernel(const void* __restrict__ src,
                                                      float* __restrict__ dst, int n,
                                                      const int* __restrict__ flag){
    int i = blockIdx.x*256 + threadIdx.x;
    if (i >= n) return;
    if (*flag){
        const unsigned short* p = (const unsigned short*)src;
        unsigned int u = ((unsigned int)p[i]) << 16;
        dst[i] = __uint_as_float(u);
    } else {
        dst[i] = ((const float*)src)[i];
    }
}

// ---------- 1D gaussian taps, normalized ----------
__global__ __launch_bounds__(128) void gkern_kernel(float* __restrict__ g){
    int t = threadIdx.x;
    if (t >= TAPS) return;
    float s = 0.f;
    for (int u = 0; u < TAPS; ++u){ float d = (float)u - 35.f; s += expf(-(d*d)/72.f); }
    float d = (float)t - 35.f;
    g[t] = expf(-(d*d)/72.f) / s;
}

// ---------- features scaled so that w = exp2(-sum(diff^2)) = exp(-0.5*d2) ----------
__global__ __launch_bounds__(256) void feat_kernel(const float* __restrict__ ref,
                                                   const float* __restrict__ kstd,
                                                   float* __restrict__ feat){
    int i = blockIdx.x*256 + threadIdx.x;
    if (i >= NPX) return;
    const float SCL = 0.84932180028801907f; // sqrt(0.5*log2(e))
    int y = i / WW, x = i - y*WW;
    float inv0 = SCL / kstd[0];
    float inv1 = SCL / kstd[1];
    float inv2 = SCL / kstd[2];
    float inv3 = SCL / kstd[3];
    float inv4 = SCL / kstd[4];
    feat[i*8+0] = (float)y * inv0;
    feat[i*8+1] = (float)x * inv1;
    feat[i*8+2] = ref[0*NPX+i] * inv2;
    feat[i*8+3] = ref[1*NPX+i] * inv3;
    feat[i*8+4] = ref[2*NPX+i] * inv4;
    feat[i*8+5] = 0.f; feat[i*8+6] = 0.f; feat[i*8+7] = 0.f;
}

// ---------- U = log(clip(u)), q0 = softmax(U) ----------
__global__ __launch_bounds__(256) void init_kernel(const float* __restrict__ unary,
                                                   float* __restrict__ U, float* __restrict__ q){
    int j = blockIdx.x*256 + threadIdx.x;
    if (j >= NPX) return;
    float u[NC]; float m = -1e30f;
    #pragma unroll
    for (int c = 0; c < NC; ++c){
        float v = unary[c*NPX+j];
        v = fminf(fmaxf(v, 1e-5f), 1.0f);
        float lg = logf(v);
        U[c*NPX+j] = lg;
        u[c] = lg;
        m = fmaxf(m, lg);
    }
    float s = 0.f;
    #pragma unroll
    for (int c = 0; c < NC; ++c){ u[c] = expf(u[c]-m); s += u[c]; }
    float inv = 1.f/s;
    #pragma unroll
    for (int c = 0; c < NC; ++c) q[c*NPX+j] = u[c]*inv;
}

__global__ __launch_bounds__(256) void zero_kernel(float* __restrict__ p, int n){
    int i = blockIdx.x*256 + threadIdx.x;
    if (i < n) p[i] = 0.f;
}

// ---------- rowsum of K (for norm) ----------
__global__ __launch_bounds__(256) void rowsum_kernel(const float* __restrict__ feat,
                                                     float* __restrict__ nacc){
    __shared__ __align__(16) float s_feat[NI*8];
    int tid = threadIdx.x;
    int i0 = blockIdx.y * NI;
    for (int s = tid; s < NI*8; s += 256) s_feat[s] = feat[i0*8 + s];
    __syncthreads();
    int j = blockIdx.x*256 + tid;
    float4 fj = *(const float4*)(feat + j*8);
    float fj4 = feat[j*8+4];
    float a = 0.f;
    #pragma unroll 2
    for (int ii = 0; ii < NI; ++ii){
        const float* sf = s_feat + ii*8;
        float dx = fj.x - sf[0], dy = fj.y - sf[1], dz = fj.z - sf[2], dw = fj.w - sf[3], d4 = fj4 - sf[4];
        float d2 = dx*dx + dy*dy + dz*dz + dw*dw + d4*d4;
        a += exp2f(-d2);
    }
    atomicAdd(&nacc[j], a);
}

__global__ __launch_bounds__(256) void normfin_kernel(const float* __restrict__ nacc,
                                                      float* __restrict__ rnorm){
    int j = blockIdx.x*256 + threadIdx.x;
    if (j >= NPX) return;
    rnorm[j] = 1.0f / (sqrtf(nacc[j]) + 1e-8f);
}

// ---------- horizontal / vertical 1D gaussian conv (zero padded) ----------
__global__ __launch_bounds__(256) void convh_kernel(const float* __restrict__ q,
                                                    float* __restrict__ o,
                                                    const float* __restrict__ g){
    int idx = blockIdx.x*256 + threadIdx.x;
    if (idx >= NC*NPX) return;
    int c = idx / NPX; int p = idx - c*NPX; int y = p / WW; int x = p - y*WW;
    const float* row = q + c*NPX + y*WW;
    int tlo = max(0, RAD - x);
    int thi = min(TAPS-1, RAD + (WW-1) - x);
    float a = 0.f;
    for (int t = tlo; t <= thi; ++t) a += g[t]*row[x + t - RAD];
    o[idx] = a;
}

__global__ __launch_bounds__(256) void convv_kernel(const float* __restrict__ q,
                                                    float* __restrict__ o,
                                                    const float* __restrict__ g){
    int idx = blockIdx.x*256 + threadIdx.x;
    if (idx >= NC*NPX) return;
    int c = idx / NPX; int p = idx - c*NPX; int y = p / WW; int x = p - y*WW;
    const float* col = q + c*NPX + x;
    int tlo = max(0, RAD - y);
    int thi = min(TAPS-1, RAD + (HH-1) - y);
    float a = 0.f;
    for (int t = tlo; t <= thi; ++t) a += g[t]*col[(y + t - RAD)*WW];
    o[idx] = a;
}

// ---------- dense bilateral: qbf[c,j] += sum_i exp2(-||fi-fj||^2) * q[c,i]/norm[i] ----------
__global__ __launch_bounds__(256) void bilateral_kernel(const float* __restrict__ q,
                                                        const float* __restrict__ feat,
                                                        const float* __restrict__ rnorm,
                                                        float* __restrict__ qbf){
    __shared__ __align__(16) float s_tmp[NI*CP];
    __shared__ __align__(16) float s_feat[NI*8];
    int tid = threadIdx.x;
    int i0 = blockIdx.y * NI;
    for (int s = tid; s < NI*8; s += 256) s_feat[s] = feat[i0*8 + s];
    for (int ii = tid; ii < NI; ii += 256){
        float rn = rnorm[i0+ii];
        #pragma unroll
        for (int c = 0; c < NC; ++c) s_tmp[ii*CP+c] = q[c*NPX + i0+ii] * rn;
        s_tmp[ii*CP+21] = 0.f; s_tmp[ii*CP+22] = 0.f; s_tmp[ii*CP+23] = 0.f;
    }
    __syncthreads();
    int j = blockIdx.x*256 + tid;
    float4 fj = *(const float4*)(feat + j*8);
    float fj4 = feat[j*8+4];
    float4 a0 = {0.f,0.f,0.f,0.f}, a1 = a0, a2 = a0, a3 = a0, a4 = a0;
    float a20 = 0.f;
    #pragma unroll 2
    for (int ii = 0; ii < NI; ++ii){
        const float* sf = s_feat + ii*8;
        float dx = fj.x - sf[0], dy = fj.y - sf[1], dz = fj.z - sf[2], dw = fj.w - sf[3], d4 = fj4 - sf[4];
        float d2 = dx*dx + dy*dy + dz*dz + dw*dw + d4*d4;
        float wgt = exp2f(-d2);
        const float4* tp = (const float4*)(s_tmp + ii*CP);
        float4 t0 = tp[0], t1 = tp[1], t2 = tp[2], t3 = tp[3], t4 = tp[4];
        float t20 = s_tmp[ii*CP+20];
        a0.x += wgt*t0.x; a0.y += wgt*t0.y; a0.z += wgt*t0.z; a0.w += wgt*t0.w;
        a1.x += wgt*t1.x; a1.y += wgt*t1.y; a1.z += wgt*t1.z; a1.w += wgt*t1.w;
        a2.x += wgt*t2.x; a2.y += wgt*t2.y; a2.z += wgt*t2.z; a2.w += wgt*t2.w;
        a3.x += wgt*t3.x; a3.y += wgt*t3.y; a3.z += wgt*t3.z; a3.w += wgt*t3.w;
        a4.x += wgt*t4.x; a4.y += wgt*t4.y; a4.z += wgt*t4.z; a4.w += wgt*t4.w;
        a20  += wgt*t20;
    }
    atomicAdd(&qbf[ 0*NPX+j], a0.x); atomicAdd(&qbf[ 1*NPX+j], a0.y);
    atomicAdd(&qbf[ 2*NPX+j], a0.z); atomicAdd(&qbf[ 3*NPX+j], a0.w);
    atomicAdd(&qbf[ 4*NPX+j], a1.x); atomicAdd(&qbf[ 5*NPX+j], a1.y);
    atomicAdd(&qbf[ 6*NPX+j], a1.z); atomicAdd(&qbf[ 7*NPX+j], a1.w);
    atomicAdd(&qbf[ 8*NPX+j], a2.x); atomicAdd(&qbf[ 9*NPX+j], a2.y);
    atomicAdd(&qbf[10*NPX+j], a2.z); atomicAdd(&qbf[11*NPX+j], a2.w);
    atomicAdd(&qbf[12*NPX+j], a3.x); atomicAdd(&qbf[13*NPX+j], a3.y);
    atomicAdd(&qbf[14*NPX+j], a3.z); atomicAdd(&qbf[15*NPX+j], a3.w);
    atomicAdd(&qbf[16*NPX+j], a4.x); atomicAdd(&qbf[17*NPX+j], a4.y);
    atomicAdd(&qbf[18*NPX+j], a4.z); atomicAdd(&qbf[19*NPX+j], a4.w);
    atomicAdd(&qbf[20*NPX+j], a20);
}

// ---------- q_hat = U + 4*qbf/norm + 2*qsf ; softmax over c ; optional output store ----------
__global__ __launch_bounds__(256) void combine_kernel(const float* __restrict__ U,
                                                      const float* __restrict__ qbf,
                                                      const float* __restrict__ qsf,
                                                      const float* __restrict__ rnorm,
                                                      float* __restrict__ qn,
                                                      void* __restrict__ outp,
                                                      const int* __restrict__ flag){
    int j = blockIdx.x*256 + threadIdx.x;
    if (j >= NPX) return;
    float rn = rnorm[j];
    float h[NC]; float m = -1e30f;
    #pragma unroll
    for (int c = 0; c < NC; ++c){
        float v = U[c*NPX+j] + 4.0f*qbf[c*NPX+j]*rn + 2.0f*qsf[c*NPX+j];
        h[c] = v; m = fmaxf(m, v);
    }
    float s = 0.f;
    #pragma unroll
    for (int c = 0; c < NC; ++c){ h[c] = expf(h[c]-m); s += h[c]; }
    float inv = 1.f/s;
    int bf = outp ? *flag : 0;
    #pragma unroll
    for (int c = 0; c < NC; ++c){
        float v = h[c]*inv;
        qn[c*NPX+j] = v;
        if (outp){
            if (bf) ((__hip_bfloat16*)outp)[c*NPX+j] = __float2bfloat16(v);
            else    ((float*)outp)[c*NPX+j] = v;
        }
    }
}

extern "C" void kernel_launch(void* const* d_in, const int* in_sizes, int n_in,
                              void* d_out, int out_size, void* d_ws, size_t ws_size,
                              hipStream_t stream) {
    int* flag = (int*)d_ws;
    float* w = (float*)d_ws + 4;
    float* unary_f = w; w += NC*NPX;
    float* ref_f   = w; w += 3*NPX;
    float* kstd_f  = w; w += 8;
    float* feat    = w; w += NPX*8;
    float* g       = w; w += 72;
    float* U       = w; w += NC*NPX;
    float* qA      = w; w += NC*NPX;
    float* qB      = w; w += NC*NPX;
    float* t1b     = w; w += NC*NPX;
    float* qsf     = w; w += NC*NPX;
    float* qbf     = w; w += NC*NPX;
    float* nacc    = w; w += NPX;
    float* rnorm   = w; w += NPX;

    hipLaunchKernelGGL(detect_kernel, dim3(1), dim3(64), 0, stream,
                       (const unsigned int*)d_in[2], flag);
    hipLaunchKernelGGL(convert_kernel, dim3(756), dim3(256), 0, stream, d_in[0], unary_f, NC*NPX, flag);
    hipLaunchKernelGGL(convert_kernel, dim3(108), dim3(256), 0, stream, d_in[1], ref_f, 3*NPX, flag);
    hipLaunchKernelGGL(convert_kernel, dim3(1),   dim3(256), 0, stream, d_in[2], kstd_f, 5, flag);

    hipLaunchKernelGGL(gkern_kernel, dim3(1), dim3(128), 0, stream, g);
    hipLaunchKernelGGL(feat_kernel, dim3(36), dim3(256), 0, stream, ref_f, kstd_f, feat);
    hipLaunchKernelGGL(init_kernel, dim3(36), dim3(256), 0, stream, unary_f, U, qA);
    hipLaunchKernelGGL(zero_kernel, dim3(36), dim3(256), 0, stream, nacc, NPX);
    hipLaunchKernelGGL(rowsum_kernel, dim3(36, NCHUNK), dim3(256), 0, stream, feat, nacc);
    hipLaunchKernelGGL(normfin_kernel, dim3(36), dim3(256), 0, stream, nacc, rnorm);

    float* qc = qA; float* qn = qB;
    for (int it = 0; it < 5; ++it){
        hipLaunchKernelGGL(convh_kernel, dim3(756), dim3(256), 0, stream, qc, t1b, g);
        hipLaunchKernelGGL(convv_kernel, dim3(756), dim3(256), 0, stream, t1b, qsf, g);
        hipLaunchKernelGGL(zero_kernel, dim3(756), dim3(256), 0, stream, qbf, NC*NPX);
        hipLaunchKernelGGL(bilateral_kernel, dim3(36, NCHUNK), dim3(256), 0, stream, qc, feat, rnorm, qbf);
        hipLaunchKernelGGL(combine_kernel, dim3(36), dim3(256), 0, stream,
                           U, qbf, qsf, rnorm, qn, (it == 4) ? d_out : (void*)nullptr, flag);
        float* tswap = qc; qc = qn; qn = tswap;
    }
}